// Round 14
// baseline (221.414 us; speedup 1.0000x reference)
//
#include <hip/hip_runtime.h>
#include <math.h>

// Problem constants (match reference)
#define NN 50000   // nodes
#define EE 800000  // edges
#define FF 128     // node features
#define CC 11      // spline coeffs per feature (G+K)
#define O2 256     // combined outputs: 128 src-proj + 128 dst-proj
#define KT 1536    // true K: 128 features x 12 slots (11 spline + silu)
#define NKC 8      // K-chunks of 192 (16 features x 12) = 6 MFMA windows
#define AROW 200   // A-tile row in shorts (192 + 8 pad)
#define NPB 768    // main proj blocks: EXACTLY 3 blocks/CU x 256 CUs (one generation)
#define NTB2 224   // tail blocks: 14 groups x 2 col-halves x 8 K-segments
#define NFB 1563   // fill blocks: ceil(EE/(256*2)) — standalone, no LDS, full occupancy
#define NPACK 424  // pack blocks: 848*128/256
#define NTN 896    // tail node slots (14*64; only 848 real)
#define CAP 64     // slot capacity per dst (max degree ~40 for E/N=16 Poisson)

typedef __attribute__((ext_vector_type(8))) short short8;
typedef __attribute__((ext_vector_type(4))) float f32x4;
typedef unsigned int uint;
typedef unsigned short ushort;

__device__ __forceinline__ ushort bf16_rne(float v) {
  uint u = __float_as_uint(v);
  u = u + 0x7FFFu + ((u >> 16) & 1u);
  return (ushort)(u >> 16);
}
__device__ __forceinline__ float bf_lo(uint u) { return __uint_as_float(u << 16); }
__device__ __forceinline__ float bf_hi(uint u) { return __uint_as_float(u & 0xffff0000u); }

// LDS-only barrier: order ds ops, then block-barrier — without the vmcnt(0)
// drain __syncthreads() emits (global loads target registers only here).
// R13: neutral vs __syncthreads (within noise); kept as harmless.
__device__ __forceinline__ void lds_barrier() {
  asm volatile("s_waitcnt lgkmcnt(0)" ::: "memory");
  __builtin_amdgcn_s_barrier();
}

// Repack weights to MFMA-fragment-contiguous bf16 layout:
// Wh[((g*16 + cg)*64 + lane)*8 + j] = W^T[col = cg*16+(lane&15)][k = g*32+(lane>>4)*8+j]
// so a wave's B-fragment load for (k-window g, col-group cg) is ONE coalesced
// 1KB read. Also zero cur (slot counters; CSR scan chain deleted entirely).
__global__ __launch_bounds__(256) void repack_zero_kernel(
    const float* __restrict__ bws, const float* __restrict__ sws,
    const float* __restrict__ bwd, const float* __restrict__ swd,
    ushort* __restrict__ Wh, int* __restrict__ cur) {
  int idx = blockIdx.x * 256 + threadIdx.x;
  if (idx < NN) cur[idx] = 0;
  if (idx >= O2 * KT) return;
  int j = idx & 7;
  int lane = (idx >> 3) & 63;
  int cg = (idx >> 9) & 15;
  int g = idx >> 13;  // 0..47
  int col = cg * 16 + (lane & 15);
  int k = g * 32 + (lane >> 4) * 8 + j;
  int f = k / 12;
  int ch = k - f * 12;
  const float* bw = (col < 128) ? bws : bwd;
  const float* sw = (col < 128) ? sws : swd;
  int o = col & 127;
  float v = (ch == 11) ? bw[(size_t)o * FF + f] : sw[((size_t)o * FF + f) * CC + ch];
  Wh[idx] = bf16_rne(v);
}

// Shared staging helper: compute 12-slot KAN row (11 cubic-spline weights +
// silu) for feature value xv into `row`.
__device__ __forceinline__ void kan_row(float xv, ushort* row) {
  row[11] = bf16_rne(xv / (1.f + __expf(-xv)));  // silu slot
  float u = fmaf(xv, 4.f, 7.f);
  float fj = floorf(u);
  int j = (int)fj;
  if (j >= 0 && j <= 13) {
    float tt = u - fj;
    float t2 = tt * tt, t3 = t2 * tt;
    float w0 = (1.f / 6.f) * (1.f - 3.f * tt + 3.f * t2 - t3);
    float w1 = (1.f / 6.f) * (4.f - 6.f * t2 + 3.f * t3);
    float w2 = (1.f / 6.f) * (1.f + 3.f * tt + 3.f * t2 - 3.f * t3);
    float w3 = (1.f / 6.f) * t3;
    float wv[4] = {w0, w1, w2, w3};
    int i0 = j - 3;
#pragma unroll
    for (int c = 0; c < 4; ++c) {
      int idx = i0 + c;
      if (idx >= 0 && idx <= 10) row[idx] = bf16_rne(wv[c]);
    }
  }
}

// Projection dispatch (R14: fill UN-FUSED — fill blocks inherited this
// kernel's 51.2KB LDS allocation and ran at 3 blocks/CU despite using no
// LDS; standalone fill runs at full occupancy). Block order: [0,NPB) main
// proj | [NPB,+NTB2) K-split tail proj (plain float2 stores).
//
// Main projection (R6 body + lds_barrier): block = 64 nodes x 256 cols,
// 4 waves (wave = 64x64 tile, acc[4][4]). K chunked by 192, cooperative
// A-stage, double-buffered A-tile, one LDS barrier per chunk. B operand
// pipelined DEPTH-2 via parity register sets (bh[2][4]); A-reads split 2+2
// (R7's grouped ap-parity regressed — keep this form). NPB=768 = one
// scheduling generation. NOTE: do NOT cap VGPRs (R4: spill disaster).
__global__ __launch_bounds__(256) void proj_tail_kernel(
    const float* __restrict__ x, const ushort* __restrict__ Wh,
    uint* __restrict__ projB, float2* __restrict__ projF) {
  __shared__ ushort Ah[2][64][AROW];  // 51.2 KB
  const int t = threadIdx.x;
  const int lane = t & 63;
  const int w = t >> 6;      // wave 0..3
  const int m = lane & 15;
  const int quad = lane >> 4;

  if (blockIdx.x >= NPB) {  // ---- K-split tail projection (no atomics) ----
    ushort(*Ath)[AROW] = Ah[0];  // single 25.6KB chunk buffer
    const int tb = blockIdx.x - NPB;
    const int ks = tb & 7;           // K-segment (chunk) 0..7
    const int rest = tb >> 3;        // 0..27
    const int tg = rest >> 1;        // node group 0..13
    const int hh = rest & 1;         // col half
    const int block0 = NPB * 64 + tg * 64;  // 49152 + tg*64
    const int gn = block0 + lane;
    const bool valid = (gn < NN);

    {
      const float4 zero4 = make_float4(0.f, 0.f, 0.f, 0.f);
      float4 xvv = valid ? *(const float4*)(x + (size_t)gn * FF + ks * 16 + w * 4) : zero4;
      float xa[4] = {xvv.x, xvv.y, xvv.z, xvv.w};
      uint4* dz = (uint4*)&Ath[lane][w * 48];
#pragma unroll
      for (int i = 0; i < 6; ++i) dz[i] = make_uint4(0u, 0u, 0u, 0u);
#pragma unroll
      for (int jf = 0; jf < 4; ++jf) kan_row(xa[jf], &Ath[lane][w * 48 + jf * 12]);
    }

    f32x4 acc[4][2];
#pragma unroll
    for (int r = 0; r < 4; ++r)
#pragma unroll
      for (int c = 0; c < 2; ++c) acc[r][c] = (f32x4)(0.f);

    short8 bh_c[2];
#pragma unroll
    for (int c = 0; c < 2; ++c)
      bh_c[c] = *(const short8*)(Wh + (size_t)((ks * 6) * 16 + hh * 8 + w * 2 + c) * 512 +
                                 (size_t)lane * 8);
    __syncthreads();

#pragma unroll
    for (int sk = 0; sk < 6; ++sk) {
      short8 bh_n[2];
      if (sk < 5) {
#pragma unroll
        for (int c = 0; c < 2; ++c)
          bh_n[c] = *(const short8*)(Wh +
                                     (size_t)((ks * 6 + sk + 1) * 16 + hh * 8 + w * 2 + c) * 512 +
                                     (size_t)lane * 8);
      }
      short8 a0 = *(const short8*)(&Ath[0 * 16 + m][sk * 32 + quad * 8]);
      short8 a1 = *(const short8*)(&Ath[1 * 16 + m][sk * 32 + quad * 8]);
      short8 a2 = *(const short8*)(&Ath[2 * 16 + m][sk * 32 + quad * 8]);
      short8 a3 = *(const short8*)(&Ath[3 * 16 + m][sk * 32 + quad * 8]);
#pragma unroll
      for (int c = 0; c < 2; ++c) {
        acc[0][c] = __builtin_amdgcn_mfma_f32_16x16x32_bf16(a0, bh_c[c], acc[0][c], 0, 0, 0);
        acc[1][c] = __builtin_amdgcn_mfma_f32_16x16x32_bf16(a1, bh_c[c], acc[1][c], 0, 0, 0);
        acc[2][c] = __builtin_amdgcn_mfma_f32_16x16x32_bf16(a2, bh_c[c], acc[2][c], 0, 0, 0);
        acc[3][c] = __builtin_amdgcn_mfma_f32_16x16x32_bf16(a3, bh_c[c], acc[3][c], 0, 0, 0);
      }
      bh_c[0] = bh_n[0];
      bh_c[1] = bh_n[1];
    }
    // plain stores into the per-K-segment slice: projF[ks][tg*64+nl][q*16+m]
    const int q = hh * 4 + w;
#pragma unroll
    for (int r = 0; r < 4; ++r) {
#pragma unroll
      for (int reg = 0; reg < 4; ++reg) {
        int nl = r * 16 + quad * 4 + reg;
        projF[(size_t)(ks * NTN + tg * 64 + nl) * 128 + q * 16 + m] =
            make_float2(acc[r][0][reg], acc[r][1][reg]);
      }
    }
    return;
  }

  // ---- main projection ----
  const int block0 = blockIdx.x * 64;
  const int gn = block0 + lane;  // staging: node = lane, feature quartet = wave

  auto stage = [&](float4 xvv, ushort(*buf)[AROW]) {
    float xa[4] = {xvv.x, xvv.y, xvv.z, xvv.w};
    uint4* dz = (uint4*)&buf[lane][w * 48];
#pragma unroll
    for (int i = 0; i < 6; ++i) dz[i] = make_uint4(0u, 0u, 0u, 0u);
#pragma unroll
    for (int jf = 0; jf < 4; ++jf) kan_row(xa[jf], &buf[lane][w * 48 + jf * 12]);
  };

  f32x4 acc[4][4];
#pragma unroll
  for (int r = 0; r < 4; ++r)
#pragma unroll
    for (int c = 0; c < 4; ++c) acc[r][c] = (f32x4)(0.f);

  float4 xv0 = *(const float4*)(x + (size_t)gn * FF + w * 4);
  stage(xv0, Ah[0]);
  float4 xv_next = *(const float4*)(x + (size_t)gn * FF + 16 + w * 4);

  // B pipeline prologue: global k-steps 0 and 1 into parity sets 0 and 1.
  short8 bh[2][4];
#pragma unroll
  for (int c = 0; c < 4; ++c) {
    bh[0][c] = *(const short8*)(Wh + (size_t)(0 * 16 + w * 4 + c) * 512 + (size_t)lane * 8);
    bh[1][c] = *(const short8*)(Wh + (size_t)(1 * 16 + w * 4 + c) * 512 + (size_t)lane * 8);
  }
  lds_barrier();

#pragma unroll 2
  for (int kc = 0; kc < NKC; ++kc) {
    float4 xv_pf = make_float4(0.f, 0.f, 0.f, 0.f);
    if (kc + 2 < NKC)
      xv_pf = *(const float4*)(x + (size_t)gn * FF + (kc + 2) * 16 + w * 4);
    if (kc + 1 < NKC) stage(xv_next, Ah[(kc + 1) & 1]);
#pragma unroll
    for (int sk = 0; sk < 6; ++sk) {
      const int p = sk & 1;
      // A fragments, split 2+2 so the first MFMA group overlaps the second read
      short8 a0 = *(const short8*)(&Ah[kc & 1][0 * 16 + m][sk * 32 + quad * 8]);
      short8 a1 = *(const short8*)(&Ah[kc & 1][1 * 16 + m][sk * 32 + quad * 8]);
#pragma unroll
      for (int c = 0; c < 4; ++c)
        acc[0][c] = __builtin_amdgcn_mfma_f32_16x16x32_bf16(a0, bh[p][c], acc[0][c], 0, 0, 0);
#pragma unroll
      for (int c = 0; c < 4; ++c)
        acc[1][c] = __builtin_amdgcn_mfma_f32_16x16x32_bf16(a1, bh[p][c], acc[1][c], 0, 0, 0);
      short8 a2 = *(const short8*)(&Ah[kc & 1][2 * 16 + m][sk * 32 + quad * 8]);
      short8 a3 = *(const short8*)(&Ah[kc & 1][3 * 16 + m][sk * 32 + quad * 8]);
#pragma unroll
      for (int c = 0; c < 4; ++c)
        acc[2][c] = __builtin_amdgcn_mfma_f32_16x16x32_bf16(a2, bh[p][c], acc[2][c], 0, 0, 0);
#pragma unroll
      for (int c = 0; c < 4; ++c)
        acc[3][c] = __builtin_amdgcn_mfma_f32_16x16x32_bf16(a3, bh[p][c], acc[3][c], 0, 0, 0);
      // refill this parity set for global step g+2 (regs just freed; WAR-safe)
      int gnc = kc * 6 + sk + 2;
      if (gnc > 47) gnc = 47;  // harmless re-read on the last two steps
#pragma unroll
      for (int c = 0; c < 4; ++c)
        bh[p][c] = *(const short8*)(Wh + (size_t)(gnc * 16 + w * 4 + c) * 512 +
                                    (size_t)lane * 8);
    }
    lds_barrier();
    xv_next = xv_pf;
  }
  // epilogue: C/D layout col=lane&15, row=quad*4+reg (verified m89/m91).
  // pack c-pairs: p = q*16 + m, q = 2w + cp -> cols (q*32+m, q*32+16+m)
#pragma unroll
  for (int r = 0; r < 4; ++r) {
#pragma unroll
    for (int reg = 0; reg < 4; ++reg) {
      int nd = block0 + r * 16 + quad * 4 + reg;
#pragma unroll
      for (int cp = 0; cp < 2; ++cp) {
        int q = 2 * w + cp;
        uint val = (uint)bf16_rne(acc[r][2 * cp][reg]) |
                   ((uint)bf16_rne(acc[r][2 * cp + 1][reg]) << 16);
        projB[(size_t)nd * 128 + q * 16 + m] = val;
      }
    }
  }
}

// Standalone edge fill (no LDS -> full occupancy): 2 edges/thread, int2
// loads, fixed-capacity slot array writes.
__global__ __launch_bounds__(256) void fill_kernel(
    const int* __restrict__ ei, int* __restrict__ cur, ushort* __restrict__ scsr) {
  int base = (blockIdx.x * 256 + threadIdx.x) * 2;
  if (base + 1 < EE) {
    int2 ss = *(const int2*)(ei + base);
    int2 dd = *(const int2*)(ei + EE + base);
    int p0 = atomicAdd(&cur[dd.x], 1);
    if (p0 < CAP) scsr[(size_t)dd.x * CAP + p0] = (ushort)ss.x;
    int p1 = atomicAdd(&cur[dd.y], 1);
    if (p1 < CAP) scsr[(size_t)dd.y * CAP + p1] = (ushort)ss.y;
  } else if (base < EE) {
    int s = ei[base], d = ei[EE + base];
    int p0 = atomicAdd(&cur[d], 1);
    if (p0 < CAP) scsr[(size_t)d * CAP + p0] = (ushort)s;
  }
}

// Tail pack: sum the 8 projF K-segment slices and pack bf16 -> projB for
// tail nodes 49152..49999.
__global__ __launch_bounds__(256) void pack_kernel(
    const float2* __restrict__ projF, uint* __restrict__ projB) {
  int wk = blockIdx.x * 256 + threadIdx.x;  // 0..108543
  int n = wk >> 7, p = wk & 127;
  if (n < 848) {
    float lo = 0.f, hi = 0.f;
#pragma unroll
    for (int ks = 0; ks < 8; ++ks) {
      float2 v = projF[(size_t)(ks * NTN + n) * 128 + p];
      lo += v.x;
      hi += v.y;
    }
    projB[(size_t)(NPB * 64 + n) * 128 + p] =
        (uint)bf16_rne(lo) | ((uint)bf16_rne(hi) << 16);
  }
}

// Per-dst aggregation: one wave per dst, 4 edges in flight (16-lane groups).
// Wave loads ALL 64 candidate src ids in one coalesced 128B read (CAP
// layout), derives gather addresses via __shfl from registers; U-pipeline
// 3-ahead. (R11-verified)
__global__ __launch_bounds__(256) void aggr_kernel(
    const uint* __restrict__ projB, const ushort* __restrict__ scsr,
    const int* __restrict__ cur, const float* __restrict__ av,
    const float* __restrict__ x, const float* __restrict__ bias,
    const float* __restrict__ pa, float* __restrict__ out) {
  int d = blockIdx.x * 4 + (threadIdx.x >> 6);
  if (d >= NN) return;
  int l = threadIdx.x & 63;
  int g = l >> 4, m = l & 15;
  const uint4* pb4 = (const uint4*)projB;
  // all candidate src ids for this dst, one per lane (coalesced 128B/wave)
  int sv = (int)scsr[(size_t)d * CAP + l];
  uint4 dpu = pb4[(size_t)d * 32 + 16 + m];
  uint du[4] = {dpu.x, dpu.y, dpu.z, dpu.w};
  float dplo[4], dphi[4], avlo[4], avhi[4];
  int cl[4];
#pragma unroll
  for (int j = 0; j < 4; ++j) {
    dplo[j] = bf_lo(du[j]);
    dphi[j] = bf_hi(du[j]);
    int p = 4 * m + j;
    cl[j] = ((p >> 4) << 5) + (p & 15);
    avlo[j] = av[cl[j]];
    avhi[j] = av[cl[j] + 16];
  }
  int cnt = cur[d];
  if (cnt > CAP) cnt = CAP;
  float acl[4] = {0.f, 0.f, 0.f, 0.f}, ach[4] = {0.f, 0.f, 0.f, 0.f};
  float den = 0.f;
  if (cnt > 0 && g < cnt) {
    const int cm = cnt - 1;
    // register-sourced src ids (clamped; dummy loads never processed)
    int e1 = g + 4, e2 = g + 8;
    int s0 = __shfl(sv, g, 64);
    int s1 = __shfl(sv, e1 < cm ? e1 : cm, 64);
    int s2 = __shfl(sv, e2 < cm ? e2 : cm, 64);
    uint4 U0 = pb4[(size_t)s0 * 32 + m];
    uint4 U1 = pb4[(size_t)s1 * 32 + m];
    uint4 U2 = pb4[(size_t)s2 * 32 + m];
    for (int e = g; e < cnt; e += 4) {
      int e3 = e + 12;
      int s3 = __shfl(sv, e3 < cm ? e3 : cm, 64);
      uint4 U3 = pb4[(size_t)s3 * 32 + m];  // 3-ahead, address from registers
      uint uu[4] = {U0.x, U0.y, U0.z, U0.w};
      float slo[4], shi[4];
      float vp = 0.f;
#pragma unroll
      for (int j = 0; j < 4; ++j) {
        slo[j] = bf_lo(uu[j]);
        shi[j] = bf_hi(uu[j]);
        float v0 = slo[j] + dplo[j];
        float v1 = shi[j] + dphi[j];
        v0 = (v0 >= 0.f) ? v0 : 0.2f * v0;
        v1 = (v1 >= 0.f) ? v1 : 0.2f * v1;
        vp = fmaf(v0, avlo[j], vp);
        vp = fmaf(v1, avhi[j], vp);
      }
      vp += __shfl_xor(vp, 1, 64);  // head-local reduce (4-lane subgroup)
      vp += __shfl_xor(vp, 2, 64);
      float e_ = __expf(vp);
#pragma unroll
      for (int j = 0; j < 4; ++j) {
        acl[j] = fmaf(e_, slo[j], acl[j]);
        ach[j] = fmaf(e_, shi[j], ach[j]);
      }
      den += e_;
      U0 = U1;
      U1 = U2;
      U2 = U3;
    }
  }
  // combine the 4 edge-groups (heads preserved: lanes with same m align)
#pragma unroll
  for (int off = 16; off < 64; off <<= 1) {
    den += __shfl_xor(den, off, 64);
#pragma unroll
    for (int j = 0; j < 4; ++j) {
      acl[j] += __shfl_xor(acl[j], off, 64);
      ach[j] += __shfl_xor(ach[j], off, 64);
    }
  }
  if (g == 0) {
    float a = pa[0];
    float r = 1.f / (den + 1e-16f);
#pragma unroll
    for (int j = 0; j < 4; ++j) {
      float o0 = acl[j] * r + x[(size_t)d * FF + cl[j]] + bias[cl[j]];
      float o1 = ach[j] * r + x[(size_t)d * FF + cl[j] + 16] + bias[cl[j] + 16];
      out[(size_t)d * FF + cl[j]] = (o0 >= 0.f) ? o0 : a * o0;
      out[(size_t)d * FF + cl[j] + 16] = (o1 >= 0.f) ? o1 : a * o1;
    }
  }
}

extern "C" void kernel_launch(void* const* d_in, const int* in_sizes, int n_in,
                              void* d_out, int out_size, void* d_ws, size_t ws_size,
                              hipStream_t stream) {
  const float* x = (const float*)d_in[0];
  const int* ei = (const int*)d_in[1];
  const float* bws = (const float*)d_in[2];
  const float* sws = (const float*)d_in[3];
  const float* bwd = (const float*)d_in[4];
  const float* swd = (const float*)d_in[5];
  const float* av = (const float*)d_in[6];
  const float* bias = (const float*)d_in[7];
  const float* pa = (const float*)d_in[8];

  // ws layout: Wh | projB | cur | scsr(ushort, NN*CAP) | projF
  ushort* Wh = (ushort*)d_ws;
  uint* projB = (uint*)(Wh + (size_t)O2 * KT);
  int* cur = (int*)(projB + (size_t)NN * 128);
  ushort* scsr = (ushort*)(cur + NN);
  float2* projF = (float2*)(scsr + (size_t)NN * CAP);  // 8*896*128 float2 (7.3 MB)

  repack_zero_kernel<<<(O2 * KT + 255) / 256, 256, 0, stream>>>(bws, sws, bwd, swd, Wh, cur);
  proj_tail_kernel<<<NPB + NTB2, 256, 0, stream>>>(x, Wh, projB, projF);
  fill_kernel<<<NFB, 256, 0, stream>>>(ei, cur, scsr);
  pack_kernel<<<NPACK, 256, 0, stream>>>(projF, projB);
  aggr_kernel<<<(NN + 3) / 4, 256, 0, stream>>>(projB, scsr, cur, av, x, bias, pa,
                                                (float*)d_out);
}

// Round 15
// 217.447 us; speedup vs baseline: 1.0182x; 1.0182x over previous
//
#include <hip/hip_runtime.h>
#include <math.h>

// Problem constants (match reference)
#define NN 50000   // nodes
#define EE 800000  // edges
#define FF 128     // node features
#define CC 11      // spline coeffs per feature (G+K)
#define O2 256     // combined outputs: 128 src-proj + 128 dst-proj
#define KT 1536    // true K: 128 features x 12 slots (11 spline + silu)
#define NKC 8      // K-chunks of 192 (16 features x 12) = 6 MFMA windows
#define AROW 200   // A-tile row in shorts (192 + 8 pad)
#define NPB 768    // main proj blocks: EXACTLY 3 blocks/CU x 256 CUs (one generation)
#define NTB2 224   // tail blocks: 14 groups x 2 col-halves x 8 K-segments
#define NFB 1563   // fill blocks: ceil(EE/(256*2))
#define NPACK 424  // pack blocks: 848*128/256
#define NTN 896    // tail node slots (14*64; only 848 real)
#define CAP 64     // max total degree consumed by aggr (max ~45 for E/N=16)
#define CAP8 24    // per-XCD slot capacity per dst (per-slice ~Poisson(2))

typedef __attribute__((ext_vector_type(8))) short short8;
typedef __attribute__((ext_vector_type(4))) float f32x4;
typedef unsigned int uint;
typedef unsigned short ushort;

__device__ __forceinline__ ushort bf16_rne(float v) {
  uint u = __float_as_uint(v);
  u = u + 0x7FFFu + ((u >> 16) & 1u);
  return (ushort)(u >> 16);
}
__device__ __forceinline__ float bf_lo(uint u) { return __uint_as_float(u << 16); }
__device__ __forceinline__ float bf_hi(uint u) { return __uint_as_float(u & 0xffff0000u); }

// LDS-only barrier (R13: neutral vs __syncthreads; kept as harmless).
__device__ __forceinline__ void lds_barrier() {
  asm volatile("s_waitcnt lgkmcnt(0)" ::: "memory");
  __builtin_amdgcn_s_barrier();
}

// Repack weights to MFMA-fragment-contiguous bf16 layout:
// Wh[((g*16 + cg)*64 + lane)*8 + j] = W^T[col = cg*16+(lane&15)][k = g*32+(lane>>4)*8+j]
// so a wave's B-fragment load for (k-window g, col-group cg) is ONE coalesced
// 1KB read. Also zero cur8 (8 XCD-private counter sets; grid 393216 threads
// covers 400000 ints via a second strided element).
__global__ __launch_bounds__(256) void repack_zero_kernel(
    const float* __restrict__ bws, const float* __restrict__ sws,
    const float* __restrict__ bwd, const float* __restrict__ swd,
    ushort* __restrict__ Wh, int* __restrict__ cur8) {
  int idx = blockIdx.x * 256 + threadIdx.x;
  if (idx < 8 * NN) cur8[idx] = 0;
  int idx2 = idx + 393216;
  if (idx2 < 8 * NN) cur8[idx2] = 0;
  if (idx >= O2 * KT) return;
  int j = idx & 7;
  int lane = (idx >> 3) & 63;
  int cg = (idx >> 9) & 15;
  int g = idx >> 13;  // 0..47
  int col = cg * 16 + (lane & 15);
  int k = g * 32 + (lane >> 4) * 8 + j;
  int f = k / 12;
  int ch = k - f * 12;
  const float* bw = (col < 128) ? bws : bwd;
  const float* sw = (col < 128) ? sws : swd;
  int o = col & 127;
  float v = (ch == 11) ? bw[(size_t)o * FF + f] : sw[((size_t)o * FF + f) * CC + ch];
  Wh[idx] = bf16_rne(v);
}

// Shared staging helper: compute 12-slot KAN row (11 cubic-spline weights +
// silu) for feature value xv into `row`.
__device__ __forceinline__ void kan_row(float xv, ushort* row) {
  row[11] = bf16_rne(xv / (1.f + __expf(-xv)));  // silu slot
  float u = fmaf(xv, 4.f, 7.f);
  float fj = floorf(u);
  int j = (int)fj;
  if (j >= 0 && j <= 13) {
    float tt = u - fj;
    float t2 = tt * tt, t3 = t2 * tt;
    float w0 = (1.f / 6.f) * (1.f - 3.f * tt + 3.f * t2 - t3);
    float w1 = (1.f / 6.f) * (4.f - 6.f * t2 + 3.f * t3);
    float w2 = (1.f / 6.f) * (1.f + 3.f * tt + 3.f * t2 - 3.f * t3);
    float w3 = (1.f / 6.f) * t3;
    float wv[4] = {w0, w1, w2, w3};
    int i0 = j - 3;
#pragma unroll
    for (int c = 0; c < 4; ++c) {
      int idx = i0 + c;
      if (idx >= 0 && idx <= 10) row[idx] = bf16_rne(wv[c]);
    }
  }
}

// Projection dispatch: [0,NPB) main proj | [NPB,+NTB2) K-split tail proj.
// Main projection (R6 body): block = 64 nodes x 256 cols, 4 waves (wave =
// 64x64 tile, acc[4][4]). K chunked by 192, cooperative A-stage, double-
// buffered A-tile, one LDS barrier per chunk. B operand pipelined DEPTH-2
// via parity register sets (bh[2][4]); A-reads split 2+2. NPB=768 = one
// scheduling generation. NOTE: do NOT cap VGPRs (R4: spill disaster).
__global__ __launch_bounds__(256) void proj_tail_kernel(
    const float* __restrict__ x, const ushort* __restrict__ Wh,
    uint* __restrict__ projB, float2* __restrict__ projF) {
  __shared__ ushort Ah[2][64][AROW];  // 51.2 KB
  const int t = threadIdx.x;
  const int lane = t & 63;
  const int w = t >> 6;      // wave 0..3
  const int m = lane & 15;
  const int quad = lane >> 4;

  if (blockIdx.x >= NPB) {  // ---- K-split tail projection (no atomics) ----
    ushort(*Ath)[AROW] = Ah[0];  // single 25.6KB chunk buffer
    const int tb = blockIdx.x - NPB;
    const int ks = tb & 7;           // K-segment (chunk) 0..7
    const int rest = tb >> 3;        // 0..27
    const int tg = rest >> 1;        // node group 0..13
    const int hh = rest & 1;         // col half
    const int block0 = NPB * 64 + tg * 64;  // 49152 + tg*64
    const int gn = block0 + lane;
    const bool valid = (gn < NN);

    {
      const float4 zero4 = make_float4(0.f, 0.f, 0.f, 0.f);
      float4 xvv = valid ? *(const float4*)(x + (size_t)gn * FF + ks * 16 + w * 4) : zero4;
      float xa[4] = {xvv.x, xvv.y, xvv.z, xvv.w};
      uint4* dz = (uint4*)&Ath[lane][w * 48];
#pragma unroll
      for (int i = 0; i < 6; ++i) dz[i] = make_uint4(0u, 0u, 0u, 0u);
#pragma unroll
      for (int jf = 0; jf < 4; ++jf) kan_row(xa[jf], &Ath[lane][w * 48 + jf * 12]);
    }

    f32x4 acc[4][2];
#pragma unroll
    for (int r = 0; r < 4; ++r)
#pragma unroll
      for (int c = 0; c < 2; ++c) acc[r][c] = (f32x4)(0.f);

    short8 bh_c[2];
#pragma unroll
    for (int c = 0; c < 2; ++c)
      bh_c[c] = *(const short8*)(Wh + (size_t)((ks * 6) * 16 + hh * 8 + w * 2 + c) * 512 +
                                 (size_t)lane * 8);
    __syncthreads();

#pragma unroll
    for (int sk = 0; sk < 6; ++sk) {
      short8 bh_n[2];
      if (sk < 5) {
#pragma unroll
        for (int c = 0; c < 2; ++c)
          bh_n[c] = *(const short8*)(Wh +
                                     (size_t)((ks * 6 + sk + 1) * 16 + hh * 8 + w * 2 + c) * 512 +
                                     (size_t)lane * 8);
      }
      short8 a0 = *(const short8*)(&Ath[0 * 16 + m][sk * 32 + quad * 8]);
      short8 a1 = *(const short8*)(&Ath[1 * 16 + m][sk * 32 + quad * 8]);
      short8 a2 = *(const short8*)(&Ath[2 * 16 + m][sk * 32 + quad * 8]);
      short8 a3 = *(const short8*)(&Ath[3 * 16 + m][sk * 32 + quad * 8]);
#pragma unroll
      for (int c = 0; c < 2; ++c) {
        acc[0][c] = __builtin_amdgcn_mfma_f32_16x16x32_bf16(a0, bh_c[c], acc[0][c], 0, 0, 0);
        acc[1][c] = __builtin_amdgcn_mfma_f32_16x16x32_bf16(a1, bh_c[c], acc[1][c], 0, 0, 0);
        acc[2][c] = __builtin_amdgcn_mfma_f32_16x16x32_bf16(a2, bh_c[c], acc[2][c], 0, 0, 0);
        acc[3][c] = __builtin_amdgcn_mfma_f32_16x16x32_bf16(a3, bh_c[c], acc[3][c], 0, 0, 0);
      }
      bh_c[0] = bh_n[0];
      bh_c[1] = bh_n[1];
    }
    // plain stores into the per-K-segment slice: projF[ks][tg*64+nl][q*16+m]
    const int q = hh * 4 + w;
#pragma unroll
    for (int r = 0; r < 4; ++r) {
#pragma unroll
      for (int reg = 0; reg < 4; ++reg) {
        int nl = r * 16 + quad * 4 + reg;
        projF[(size_t)(ks * NTN + tg * 64 + nl) * 128 + q * 16 + m] =
            make_float2(acc[r][0][reg], acc[r][1][reg]);
      }
    }
    return;
  }

  // ---- main projection ----
  const int block0 = blockIdx.x * 64;
  const int gn = block0 + lane;  // staging: node = lane, feature quartet = wave

  auto stage = [&](float4 xvv, ushort(*buf)[AROW]) {
    float xa[4] = {xvv.x, xvv.y, xvv.z, xvv.w};
    uint4* dz = (uint4*)&buf[lane][w * 48];
#pragma unroll
    for (int i = 0; i < 6; ++i) dz[i] = make_uint4(0u, 0u, 0u, 0u);
#pragma unroll
    for (int jf = 0; jf < 4; ++jf) kan_row(xa[jf], &buf[lane][w * 48 + jf * 12]);
  };

  f32x4 acc[4][4];
#pragma unroll
  for (int r = 0; r < 4; ++r)
#pragma unroll
    for (int c = 0; c < 4; ++c) acc[r][c] = (f32x4)(0.f);

  float4 xv0 = *(const float4*)(x + (size_t)gn * FF + w * 4);
  stage(xv0, Ah[0]);
  float4 xv_next = *(const float4*)(x + (size_t)gn * FF + 16 + w * 4);

  // B pipeline prologue: global k-steps 0 and 1 into parity sets 0 and 1.
  short8 bh[2][4];
#pragma unroll
  for (int c = 0; c < 4; ++c) {
    bh[0][c] = *(const short8*)(Wh + (size_t)(0 * 16 + w * 4 + c) * 512 + (size_t)lane * 8);
    bh[1][c] = *(const short8*)(Wh + (size_t)(1 * 16 + w * 4 + c) * 512 + (size_t)lane * 8);
  }
  lds_barrier();

#pragma unroll 2
  for (int kc = 0; kc < NKC; ++kc) {
    float4 xv_pf = make_float4(0.f, 0.f, 0.f, 0.f);
    if (kc + 2 < NKC)
      xv_pf = *(const float4*)(x + (size_t)gn * FF + (kc + 2) * 16 + w * 4);
    if (kc + 1 < NKC) stage(xv_next, Ah[(kc + 1) & 1]);
#pragma unroll
    for (int sk = 0; sk < 6; ++sk) {
      const int p = sk & 1;
      // A fragments, split 2+2 so the first MFMA group overlaps the second read
      short8 a0 = *(const short8*)(&Ah[kc & 1][0 * 16 + m][sk * 32 + quad * 8]);
      short8 a1 = *(const short8*)(&Ah[kc & 1][1 * 16 + m][sk * 32 + quad * 8]);
#pragma unroll
      for (int c = 0; c < 4; ++c)
        acc[0][c] = __builtin_amdgcn_mfma_f32_16x16x32_bf16(a0, bh[p][c], acc[0][c], 0, 0, 0);
#pragma unroll
      for (int c = 0; c < 4; ++c)
        acc[1][c] = __builtin_amdgcn_mfma_f32_16x16x32_bf16(a1, bh[p][c], acc[1][c], 0, 0, 0);
      short8 a2 = *(const short8*)(&Ah[kc & 1][2 * 16 + m][sk * 32 + quad * 8]);
      short8 a3 = *(const short8*)(&Ah[kc & 1][3 * 16 + m][sk * 32 + quad * 8]);
#pragma unroll
      for (int c = 0; c < 4; ++c)
        acc[2][c] = __builtin_amdgcn_mfma_f32_16x16x32_bf16(a2, bh[p][c], acc[2][c], 0, 0, 0);
#pragma unroll
      for (int c = 0; c < 4; ++c)
        acc[3][c] = __builtin_amdgcn_mfma_f32_16x16x32_bf16(a3, bh[p][c], acc[3][c], 0, 0, 0);
      // refill this parity set for global step g+2 (regs just freed; WAR-safe)
      int gnc = kc * 6 + sk + 2;
      if (gnc > 47) gnc = 47;  // harmless re-read on the last two steps
#pragma unroll
      for (int c = 0; c < 4; ++c)
        bh[p][c] = *(const short8*)(Wh + (size_t)(gnc * 16 + w * 4 + c) * 512 +
                                    (size_t)lane * 8);
    }
    lds_barrier();
    xv_next = xv_pf;
  }
  // epilogue: C/D layout col=lane&15, row=quad*4+reg (verified m89/m91).
  // pack c-pairs: p = q*16 + m, q = 2w + cp -> cols (q*32+m, q*32+16+m)
#pragma unroll
  for (int r = 0; r < 4; ++r) {
#pragma unroll
    for (int reg = 0; reg < 4; ++reg) {
      int nd = block0 + r * 16 + quad * 4 + reg;
#pragma unroll
      for (int cp = 0; cp < 2; ++cp) {
        int q = 2 * w + cp;
        uint val = (uint)bf16_rne(acc[r][2 * cp][reg]) |
                   ((uint)bf16_rne(acc[r][2 * cp + 1][reg]) << 16);
        projB[(size_t)nd * 128 + q * 16 + m] = val;
      }
    }
  }
}

// Edge fill, XCD-PRIVATE (R15): R14 counters showed fill is HBM-bound on
// cross-XCD line thrash — 44.5MB WRITE for 1.6MB of payload (~7 writebacks
// per scsr line; per-XCD L2s are not coherent, so stores from different
// XCDs to the same line ping-pong through HBM). Fix: each block writes only
// its own XCD's slice cur8[xcc][d] / scsr8[xcc][d][p] — every line touched
// by exactly ONE XCD -> stays dirty in local L2, one writeback. Same-address
// atomic collisions also drop 16 -> ~2.
__global__ __launch_bounds__(256) void fill_kernel(
    const int* __restrict__ ei, int* __restrict__ cur8, ushort* __restrict__ scsr8) {
  uint xcc;
  asm volatile("s_getreg_b32 %0, hwreg(HW_REG_XCC_ID)" : "=s"(xcc));
  xcc &= 7;
  int base = (blockIdx.x * 256 + threadIdx.x) * 2;
  if (base + 1 < EE) {
    int2 ss = *(const int2*)(ei + base);
    int2 dd = *(const int2*)(ei + EE + base);
    size_t b0 = (size_t)xcc * NN + dd.x;
    int p0 = atomicAdd(&cur8[b0], 1);
    if (p0 < CAP8) scsr8[b0 * CAP8 + p0] = (ushort)ss.x;
    size_t b1 = (size_t)xcc * NN + dd.y;
    int p1 = atomicAdd(&cur8[b1], 1);
    if (p1 < CAP8) scsr8[b1 * CAP8 + p1] = (ushort)ss.y;
  } else if (base < EE) {
    int s = ei[base], d = ei[EE + base];
    size_t b0 = (size_t)xcc * NN + d;
    int p0 = atomicAdd(&cur8[b0], 1);
    if (p0 < CAP8) scsr8[b0 * CAP8 + p0] = (ushort)s;
  }
}

// Tail pack: sum the 8 projF K-segment slices and pack bf16 -> projB for
// tail nodes 49152..49999.
__global__ __launch_bounds__(256) void pack_kernel(
    const float2* __restrict__ projF, uint* __restrict__ projB) {
  int wk = blockIdx.x * 256 + threadIdx.x;  // 0..108543
  int n = wk >> 7, p = wk & 127;
  if (n < 848) {
    float lo = 0.f, hi = 0.f;
#pragma unroll
    for (int ks = 0; ks < 8; ++ks) {
      float2 v = projF[(size_t)(ks * NTN + n) * 128 + p];
      lo += v.x;
      hi += v.y;
    }
    projB[(size_t)(NPB * 64 + n) * 128 + p] =
        (uint)bf16_rne(lo) | ((uint)bf16_rne(hi) << 16);
  }
}

// Per-dst aggregation: one wave per dst, 4 edges in flight (16-lane groups).
// R15 intake: per lane, read the 8 XCD-slice counts, prefix-sum, map lane l
// -> (slice, slot) of the concatenated list, load its src id. Rest of the
// pipeline (register-shfl addresses, 3-ahead U-pipeline) is R11-verified.
__global__ __launch_bounds__(256) void aggr_kernel(
    const uint* __restrict__ projB, const ushort* __restrict__ scsr8,
    const int* __restrict__ cur8, const float* __restrict__ av,
    const float* __restrict__ x, const float* __restrict__ bias,
    const float* __restrict__ pa, float* __restrict__ out) {
  int d = blockIdx.x * 4 + (threadIdx.x >> 6);
  if (d >= NN) return;
  int l = threadIdx.x & 63;
  int g = l >> 4, m = l & 15;
  const uint4* pb4 = (const uint4*)projB;
  // gather this dst's slice counts and map lane l -> (slice mys, slot myi)
  int c8[8];
#pragma unroll
  for (int s = 0; s < 8; ++s) {
    int cs = cur8[(size_t)s * NN + d];
    c8[s] = (cs > CAP8) ? CAP8 : cs;
  }
  int acc0 = 0, mys = -1, myi = 0;
#pragma unroll
  for (int s = 0; s < 8; ++s) {
    if (mys < 0 && l < acc0 + c8[s]) { mys = s; myi = l - acc0; }
    acc0 += c8[s];
  }
  int cnt = (acc0 > CAP) ? CAP : acc0;
  int sv = 0;
  if (mys >= 0 && l < CAP)
    sv = (int)scsr8[((size_t)mys * NN + d) * CAP8 + myi];

  uint4 dpu = pb4[(size_t)d * 32 + 16 + m];
  uint du[4] = {dpu.x, dpu.y, dpu.z, dpu.w};
  float dplo[4], dphi[4], avlo[4], avhi[4];
  int cl[4];
#pragma unroll
  for (int j = 0; j < 4; ++j) {
    dplo[j] = bf_lo(du[j]);
    dphi[j] = bf_hi(du[j]);
    int p = 4 * m + j;
    cl[j] = ((p >> 4) << 5) + (p & 15);
    avlo[j] = av[cl[j]];
    avhi[j] = av[cl[j] + 16];
  }
  float acl[4] = {0.f, 0.f, 0.f, 0.f}, ach[4] = {0.f, 0.f, 0.f, 0.f};
  float den = 0.f;
  if (cnt > 0 && g < cnt) {
    const int cm = cnt - 1;
    // register-sourced src ids (clamped; dummy loads never processed)
    int e1 = g + 4, e2 = g + 8;
    int s0 = __shfl(sv, g, 64);
    int s1 = __shfl(sv, e1 < cm ? e1 : cm, 64);
    int s2 = __shfl(sv, e2 < cm ? e2 : cm, 64);
    uint4 U0 = pb4[(size_t)s0 * 32 + m];
    uint4 U1 = pb4[(size_t)s1 * 32 + m];
    uint4 U2 = pb4[(size_t)s2 * 32 + m];
    for (int e = g; e < cnt; e += 4) {
      int e3 = e + 12;
      int s3 = __shfl(sv, e3 < cm ? e3 : cm, 64);
      uint4 U3 = pb4[(size_t)s3 * 32 + m];  // 3-ahead, address from registers
      uint uu[4] = {U0.x, U0.y, U0.z, U0.w};
      float slo[4], shi[4];
      float vp = 0.f;
#pragma unroll
      for (int j = 0; j < 4; ++j) {
        slo[j] = bf_lo(uu[j]);
        shi[j] = bf_hi(uu[j]);
        float v0 = slo[j] + dplo[j];
        float v1 = shi[j] + dphi[j];
        v0 = (v0 >= 0.f) ? v0 : 0.2f * v0;
        v1 = (v1 >= 0.f) ? v1 : 0.2f * v1;
        vp = fmaf(v0, avlo[j], vp);
        vp = fmaf(v1, avhi[j], vp);
      }
      vp += __shfl_xor(vp, 1, 64);  // head-local reduce (4-lane subgroup)
      vp += __shfl_xor(vp, 2, 64);
      float e_ = __expf(vp);
#pragma unroll
      for (int j = 0; j < 4; ++j) {
        acl[j] = fmaf(e_, slo[j], acl[j]);
        ach[j] = fmaf(e_, shi[j], ach[j]);
      }
      den += e_;
      U0 = U1;
      U1 = U2;
      U2 = U3;
    }
  }
  // combine the 4 edge-groups (heads preserved: lanes with same m align)
#pragma unroll
  for (int off = 16; off < 64; off <<= 1) {
    den += __shfl_xor(den, off, 64);
#pragma unroll
    for (int j = 0; j < 4; ++j) {
      acl[j] += __shfl_xor(acl[j], off, 64);
      ach[j] += __shfl_xor(ach[j], off, 64);
    }
  }
  if (g == 0) {
    float a = pa[0];
    float r = 1.f / (den + 1e-16f);
#pragma unroll
    for (int j = 0; j < 4; ++j) {
      float o0 = acl[j] * r + x[(size_t)d * FF + cl[j]] + bias[cl[j]];
      float o1 = ach[j] * r + x[(size_t)d * FF + cl[j] + 16] + bias[cl[j] + 16];
      out[(size_t)d * FF + cl[j]] = (o0 >= 0.f) ? o0 : a * o0;
      out[(size_t)d * FF + cl[j] + 16] = (o1 >= 0.f) ? o1 : a * o1;
    }
  }
}

extern "C" void kernel_launch(void* const* d_in, const int* in_sizes, int n_in,
                              void* d_out, int out_size, void* d_ws, size_t ws_size,
                              hipStream_t stream) {
  const float* x = (const float*)d_in[0];
  const int* ei = (const int*)d_in[1];
  const float* bws = (const float*)d_in[2];
  const float* sws = (const float*)d_in[3];
  const float* bwd = (const float*)d_in[4];
  const float* swd = (const float*)d_in[5];
  const float* av = (const float*)d_in[6];
  const float* bias = (const float*)d_in[7];
  const float* pa = (const float*)d_in[8];

  // ws layout: Wh | projB | cur8(8*NN int) | scsr8(8*NN*CAP8 ushort) | projF
  ushort* Wh = (ushort*)d_ws;
  uint* projB = (uint*)(Wh + (size_t)O2 * KT);
  int* cur8 = (int*)(projB + (size_t)NN * 128);
  ushort* scsr8 = (ushort*)(cur8 + 8 * NN);
  float2* projF = (float2*)(scsr8 + (size_t)8 * NN * CAP8);  // 7.3 MB

  repack_zero_kernel<<<(O2 * KT + 255) / 256, 256, 0, stream>>>(bws, sws, bwd, swd, Wh, cur8);
  proj_tail_kernel<<<NPB + NTB2, 256, 0, stream>>>(x, Wh, projB, projF);
  fill_kernel<<<NFB, 256, 0, stream>>>(ei, cur8, scsr8);
  pack_kernel<<<NPACK, 256, 0, stream>>>(projF, projB);
  aggr_kernel<<<(NN + 3) / 4, 256, 0, stream>>>(projB, scsr8, cur8, av, x, bias, pa,
                                                (float*)d_out);
}

// Round 16
// 201.851 us; speedup vs baseline: 1.0969x; 1.0773x over previous
//
#include <hip/hip_runtime.h>
#include <math.h>

// Problem constants (match reference)
#define NN 50000   // nodes
#define EE 800000  // edges
#define FF 128     // node features
#define CC 11      // spline coeffs per feature (G+K)
#define O2 256     // combined outputs: 128 src-proj + 128 dst-proj
#define KT 1536    // true K: 128 features x 12 slots (11 spline + silu)
#define NKC 8      // K-chunks of 192 (16 features x 12) = 6 MFMA windows
#define AROW 200   // A-tile row in shorts (192 + 8 pad)
#define NPB 768    // main proj blocks: EXACTLY 3 blocks/CU x 256 CUs (one generation)
#define NTB2 224   // tail blocks: 14 groups x 2 col-halves x 8 K-segments
#define NPACK 424  // pack blocks: 848*128/256
#define NTN 896    // tail node slots (14*64; only 848 real)
#define CAP 64     // slot capacity per dst (max degree ~45 for E/N=16 Poisson)

typedef __attribute__((ext_vector_type(8))) short short8;
typedef __attribute__((ext_vector_type(4))) float f32x4;
typedef unsigned int uint;
typedef unsigned short ushort;

__device__ __forceinline__ ushort bf16_rne(float v) {
  uint u = __float_as_uint(v);
  u = u + 0x7FFFu + ((u >> 16) & 1u);
  return (ushort)(u >> 16);
}
__device__ __forceinline__ float bf_lo(uint u) { return __uint_as_float(u << 16); }
__device__ __forceinline__ float bf_hi(uint u) { return __uint_as_float(u & 0xffff0000u); }

// LDS-only barrier: orders ds ops + block-barrier WITHOUT draining vmcnt.
// Critical for R16: the embedded edge-fill atomics/stores stay in flight
// across chunk barriers (no cross-wave hazard — consumed next dispatch).
__device__ __forceinline__ void lds_barrier() {
  asm volatile("s_waitcnt lgkmcnt(0)" ::: "memory");
  __builtin_amdgcn_s_barrier();
}

// Repack weights to MFMA-fragment-contiguous bf16 layout:
// Wh[((g*16 + cg)*64 + lane)*8 + j] = W^T[col = cg*16+(lane&15)][k = g*32+(lane>>4)*8+j]
// so a wave's B-fragment load for (k-window g, col-group cg) is ONE coalesced
// 1KB read. Also zero cur (slot counters).
__global__ __launch_bounds__(256) void repack_zero_kernel(
    const float* __restrict__ bws, const float* __restrict__ sws,
    const float* __restrict__ bwd, const float* __restrict__ swd,
    ushort* __restrict__ Wh, int* __restrict__ cur) {
  int idx = blockIdx.x * 256 + threadIdx.x;
  if (idx < NN) cur[idx] = 0;
  if (idx >= O2 * KT) return;
  int j = idx & 7;
  int lane = (idx >> 3) & 63;
  int cg = (idx >> 9) & 15;
  int g = idx >> 13;  // 0..47
  int col = cg * 16 + (lane & 15);
  int k = g * 32 + (lane >> 4) * 8 + j;
  int f = k / 12;
  int ch = k - f * 12;
  const float* bw = (col < 128) ? bws : bwd;
  const float* sw = (col < 128) ? sws : swd;
  int o = col & 127;
  float v = (ch == 11) ? bw[(size_t)o * FF + f] : sw[((size_t)o * FF + f) * CC + ch];
  Wh[idx] = bf16_rne(v);
}

// Shared staging helper: compute 12-slot KAN row (11 cubic-spline weights +
// silu) for feature value xv into `row`.
__device__ __forceinline__ void kan_row(float xv, ushort* row) {
  row[11] = bf16_rne(xv / (1.f + __expf(-xv)));  // silu slot
  float u = fmaf(xv, 4.f, 7.f);
  float fj = floorf(u);
  int j = (int)fj;
  if (j >= 0 && j <= 13) {
    float tt = u - fj;
    float t2 = tt * tt, t3 = t2 * tt;
    float w0 = (1.f / 6.f) * (1.f - 3.f * tt + 3.f * t2 - t3);
    float w1 = (1.f / 6.f) * (4.f - 6.f * t2 + 3.f * t3);
    float w2 = (1.f / 6.f) * (1.f + 3.f * tt + 3.f * t2 - 3.f * t3);
    float w3 = (1.f / 6.f) * t3;
    float wv[4] = {w0, w1, w2, w3};
    int i0 = j - 3;
#pragma unroll
    for (int c = 0; c < 4; ++c) {
      int idx = i0 + c;
      if (idx >= 0 && idx <= 10) row[idx] = bf16_rne(wv[c]);
    }
  }
}

// Projection dispatch: [0,NPB) main proj (with EMBEDDED edge-fill pipeline)
// | [NPB,+NTB2) K-split tail proj.
//
// R16: standalone fill costs a fixed ~50us (atomic-MLP x latency bound —
// invariant under contention/XCD/pattern changes, R12/R14/R15). Fix: hide
// it. Each main-proj chunk kc runs a 3-stage pipeline: (1) scatter-store the
// edge whose atomic issued at kc-1; (2) issue atomicAdd for the edge loaded
// at kc-1; (3) load ei for chunk kc+1. Every op has a full chunk (~1us of
// MFMA) between issue and use; lgkm-only barriers keep them in flight.
// Chunks 0..4 x 768 blocks x 256 threads cover all 800K edges.
//
// Main projection (R6 body): block = 64 nodes x 256 cols, 4 waves (wave =
// 64x64 tile, acc[4][4]). K chunked by 192, cooperative A-stage, double-
// buffered A-tile. B pipelined DEPTH-2 via parity sets (bh[2][4]); A-reads
// split 2+2. NPB=768 = one generation. Do NOT cap VGPRs (R4).
__global__ __launch_bounds__(256) void proj_fill_kernel(
    const float* __restrict__ x, const ushort* __restrict__ Wh,
    uint* __restrict__ projB, float2* __restrict__ projF,
    const int* __restrict__ ei, int* __restrict__ cur, ushort* __restrict__ scsr) {
  __shared__ ushort Ah[2][64][AROW];  // 51.2 KB
  const int t = threadIdx.x;
  const int lane = t & 63;
  const int w = t >> 6;      // wave 0..3
  const int m = lane & 15;
  const int quad = lane >> 4;

  if (blockIdx.x >= NPB) {  // ---- K-split tail projection (no atomics) ----
    ushort(*Ath)[AROW] = Ah[0];  // single 25.6KB chunk buffer
    const int tb = blockIdx.x - NPB;
    const int ks = tb & 7;           // K-segment (chunk) 0..7
    const int rest = tb >> 3;        // 0..27
    const int tg = rest >> 1;        // node group 0..13
    const int hh = rest & 1;         // col half
    const int block0 = NPB * 64 + tg * 64;  // 49152 + tg*64
    const int gn = block0 + lane;
    const bool valid = (gn < NN);

    {
      const float4 zero4 = make_float4(0.f, 0.f, 0.f, 0.f);
      float4 xvv = valid ? *(const float4*)(x + (size_t)gn * FF + ks * 16 + w * 4) : zero4;
      float xa[4] = {xvv.x, xvv.y, xvv.z, xvv.w};
      uint4* dz = (uint4*)&Ath[lane][w * 48];
#pragma unroll
      for (int i = 0; i < 6; ++i) dz[i] = make_uint4(0u, 0u, 0u, 0u);
#pragma unroll
      for (int jf = 0; jf < 4; ++jf) kan_row(xa[jf], &Ath[lane][w * 48 + jf * 12]);
    }

    f32x4 acc[4][2];
#pragma unroll
    for (int r = 0; r < 4; ++r)
#pragma unroll
      for (int c = 0; c < 2; ++c) acc[r][c] = (f32x4)(0.f);

    short8 bh_c[2];
#pragma unroll
    for (int c = 0; c < 2; ++c)
      bh_c[c] = *(const short8*)(Wh + (size_t)((ks * 6) * 16 + hh * 8 + w * 2 + c) * 512 +
                                 (size_t)lane * 8);
    __syncthreads();

#pragma unroll
    for (int sk = 0; sk < 6; ++sk) {
      short8 bh_n[2];
      if (sk < 5) {
#pragma unroll
        for (int c = 0; c < 2; ++c)
          bh_n[c] = *(const short8*)(Wh +
                                     (size_t)((ks * 6 + sk + 1) * 16 + hh * 8 + w * 2 + c) * 512 +
                                     (size_t)lane * 8);
      }
      short8 a0 = *(const short8*)(&Ath[0 * 16 + m][sk * 32 + quad * 8]);
      short8 a1 = *(const short8*)(&Ath[1 * 16 + m][sk * 32 + quad * 8]);
      short8 a2 = *(const short8*)(&Ath[2 * 16 + m][sk * 32 + quad * 8]);
      short8 a3 = *(const short8*)(&Ath[3 * 16 + m][sk * 32 + quad * 8]);
#pragma unroll
      for (int c = 0; c < 2; ++c) {
        acc[0][c] = __builtin_amdgcn_mfma_f32_16x16x32_bf16(a0, bh_c[c], acc[0][c], 0, 0, 0);
        acc[1][c] = __builtin_amdgcn_mfma_f32_16x16x32_bf16(a1, bh_c[c], acc[1][c], 0, 0, 0);
        acc[2][c] = __builtin_amdgcn_mfma_f32_16x16x32_bf16(a2, bh_c[c], acc[2][c], 0, 0, 0);
        acc[3][c] = __builtin_amdgcn_mfma_f32_16x16x32_bf16(a3, bh_c[c], acc[3][c], 0, 0, 0);
      }
      bh_c[0] = bh_n[0];
      bh_c[1] = bh_n[1];
    }
    // plain stores into the per-K-segment slice: projF[ks][tg*64+nl][q*16+m]
    const int q = hh * 4 + w;
#pragma unroll
    for (int r = 0; r < 4; ++r) {
#pragma unroll
      for (int reg = 0; reg < 4; ++reg) {
        int nl = r * 16 + quad * 4 + reg;
        projF[(size_t)(ks * NTN + tg * 64 + nl) * 128 + q * 16 + m] =
            make_float2(acc[r][0][reg], acc[r][1][reg]);
      }
    }
    return;
  }

  // ---- main projection (+ embedded edge-fill pipeline) ----
  const int block0 = blockIdx.x * 64;
  const int gn = block0 + lane;  // staging: node = lane, feature quartet = wave

  auto stage = [&](float4 xvv, ushort(*buf)[AROW]) {
    float xa[4] = {xvv.x, xvv.y, xvv.z, xvv.w};
    uint4* dz = (uint4*)&buf[lane][w * 48];
#pragma unroll
    for (int i = 0; i < 6; ++i) dz[i] = make_uint4(0u, 0u, 0u, 0u);
#pragma unroll
    for (int jf = 0; jf < 4; ++jf) kan_row(xa[jf], &buf[lane][w * 48 + jf * 12]);
  };

  f32x4 acc[4][4];
#pragma unroll
  for (int r = 0; r < 4; ++r)
#pragma unroll
    for (int c = 0; c < 4; ++c) acc[r][c] = (f32x4)(0.f);

  float4 xv0 = *(const float4*)(x + (size_t)gn * FF + w * 4);
  stage(xv0, Ah[0]);
  float4 xv_next = *(const float4*)(x + (size_t)gn * FF + 16 + w * 4);

  // B pipeline prologue: global k-steps 0 and 1 into parity sets 0 and 1.
  short8 bh[2][4];
#pragma unroll
  for (int c = 0; c < 4; ++c) {
    bh[0][c] = *(const short8*)(Wh + (size_t)(0 * 16 + w * 4 + c) * 512 + (size_t)lane * 8);
    bh[1][c] = *(const short8*)(Wh + (size_t)(1 * 16 + w * 4 + c) * 512 + (size_t)lane * 8);
  }
  // edge-fill pipeline state
  int ls = 0, ld = 0;        // loaded edge (src, dst)
  int as_ = 0, ad = 0, ap = 0;  // atomic-issued edge (src, dst, slot)
  bool lv = false, av_ = false;
  lds_barrier();

#pragma unroll 2
  for (int kc = 0; kc < NKC; ++kc) {
    float4 xv_pf = make_float4(0.f, 0.f, 0.f, 0.f);
    if (kc + 2 < NKC)
      xv_pf = *(const float4*)(x + (size_t)gn * FF + (kc + 2) * 16 + w * 4);
    if (kc + 1 < NKC) stage(xv_next, Ah[(kc + 1) & 1]);
    // ---- embedded edge-fill, 3-stage (store kc-2's edge, atomic kc-1's,
    // load kc's). All latencies hide under this chunk's MFMA work. ----
    if (av_) {
      if (ap < CAP) scsr[(size_t)ad * CAP + ap] = (ushort)as_;
      av_ = false;
    }
    if (lv) {
      ap = atomicAdd(&cur[ld], 1);
      ad = ld; as_ = ls; av_ = true; lv = false;
    }
    {
      int e = (kc * NPB + (int)blockIdx.x) * 256 + t;
      if (e < EE) {
        ls = ei[e];
        ld = ei[EE + e];
        lv = true;
      }
    }
#pragma unroll
    for (int sk = 0; sk < 6; ++sk) {
      const int p = sk & 1;
      // A fragments, split 2+2 so the first MFMA group overlaps the second read
      short8 a0 = *(const short8*)(&Ah[kc & 1][0 * 16 + m][sk * 32 + quad * 8]);
      short8 a1 = *(const short8*)(&Ah[kc & 1][1 * 16 + m][sk * 32 + quad * 8]);
#pragma unroll
      for (int c = 0; c < 4; ++c)
        acc[0][c] = __builtin_amdgcn_mfma_f32_16x16x32_bf16(a0, bh[p][c], acc[0][c], 0, 0, 0);
#pragma unroll
      for (int c = 0; c < 4; ++c)
        acc[1][c] = __builtin_amdgcn_mfma_f32_16x16x32_bf16(a1, bh[p][c], acc[1][c], 0, 0, 0);
      short8 a2 = *(const short8*)(&Ah[kc & 1][2 * 16 + m][sk * 32 + quad * 8]);
      short8 a3 = *(const short8*)(&Ah[kc & 1][3 * 16 + m][sk * 32 + quad * 8]);
#pragma unroll
      for (int c = 0; c < 4; ++c)
        acc[2][c] = __builtin_amdgcn_mfma_f32_16x16x32_bf16(a2, bh[p][c], acc[2][c], 0, 0, 0);
#pragma unroll
      for (int c = 0; c < 4; ++c)
        acc[3][c] = __builtin_amdgcn_mfma_f32_16x16x32_bf16(a3, bh[p][c], acc[3][c], 0, 0, 0);
      // refill this parity set for global step g+2 (regs just freed; WAR-safe)
      int gnc = kc * 6 + sk + 2;
      if (gnc > 47) gnc = 47;  // harmless re-read on the last two steps
#pragma unroll
      for (int c = 0; c < 4; ++c)
        bh[p][c] = *(const short8*)(Wh + (size_t)(gnc * 16 + w * 4 + c) * 512 +
                                    (size_t)lane * 8);
    }
    lds_barrier();
    xv_next = xv_pf;
  }
  // flush edge-fill pipeline
  if (av_) {
    if (ap < CAP) scsr[(size_t)ad * CAP + ap] = (ushort)as_;
  }
  if (lv) {
    int p2 = atomicAdd(&cur[ld], 1);
    if (p2 < CAP) scsr[(size_t)ld * CAP + p2] = (ushort)ls;
  }
  // epilogue: C/D layout col=lane&15, row=quad*4+reg (verified m89/m91).
  // pack c-pairs: p = q*16 + m, q = 2w + cp -> cols (q*32+m, q*32+16+m)
#pragma unroll
  for (int r = 0; r < 4; ++r) {
#pragma unroll
    for (int reg = 0; reg < 4; ++reg) {
      int nd = block0 + r * 16 + quad * 4 + reg;
#pragma unroll
      for (int cp = 0; cp < 2; ++cp) {
        int q = 2 * w + cp;
        uint val = (uint)bf16_rne(acc[r][2 * cp][reg]) |
                   ((uint)bf16_rne(acc[r][2 * cp + 1][reg]) << 16);
        projB[(size_t)nd * 128 + q * 16 + m] = val;
      }
    }
  }
}

// Tail pack: sum the 8 projF K-segment slices and pack bf16 -> projB for
// tail nodes 49152..49999.
__global__ __launch_bounds__(256) void pack_kernel(
    const float2* __restrict__ projF, uint* __restrict__ projB) {
  int wk = blockIdx.x * 256 + threadIdx.x;  // 0..108543
  int n = wk >> 7, p = wk & 127;
  if (n < 848) {
    float lo = 0.f, hi = 0.f;
#pragma unroll
    for (int ks = 0; ks < 8; ++ks) {
      float2 v = projF[(size_t)(ks * NTN + n) * 128 + p];
      lo += v.x;
      hi += v.y;
    }
    projB[(size_t)(NPB * 64 + n) * 128 + p] =
        (uint)bf16_rne(lo) | ((uint)bf16_rne(hi) << 16);
  }
}

// Per-dst aggregation: one wave per dst, 4 edges in flight (16-lane groups).
// Wave loads ALL 64 candidate src ids in one coalesced 128B read (CAP
// layout), derives gather addresses via __shfl from registers; U-pipeline
// 3-ahead. R16 trims: leaky via fmaxf(v, 0.2v) (2 ops vs 3), unroll-2 on
// the edge loop (renames away the U-register rotation movs).
__global__ __launch_bounds__(256) void aggr_kernel(
    const uint* __restrict__ projB, const ushort* __restrict__ scsr,
    const int* __restrict__ cur, const float* __restrict__ av,
    const float* __restrict__ x, const float* __restrict__ bias,
    const float* __restrict__ pa, float* __restrict__ out) {
  int d = blockIdx.x * 4 + (threadIdx.x >> 6);
  if (d >= NN) return;
  int l = threadIdx.x & 63;
  int g = l >> 4, m = l & 15;
  const uint4* pb4 = (const uint4*)projB;
  // all candidate src ids for this dst, one per lane (coalesced 128B/wave)
  int sv = (int)scsr[(size_t)d * CAP + l];
  uint4 dpu = pb4[(size_t)d * 32 + 16 + m];
  uint du[4] = {dpu.x, dpu.y, dpu.z, dpu.w};
  float dplo[4], dphi[4], avlo[4], avhi[4];
  int cl[4];
#pragma unroll
  for (int j = 0; j < 4; ++j) {
    dplo[j] = bf_lo(du[j]);
    dphi[j] = bf_hi(du[j]);
    int p = 4 * m + j;
    cl[j] = ((p >> 4) << 5) + (p & 15);
    avlo[j] = av[cl[j]];
    avhi[j] = av[cl[j] + 16];
  }
  int cnt = cur[d];
  if (cnt > CAP) cnt = CAP;
  float acl[4] = {0.f, 0.f, 0.f, 0.f}, ach[4] = {0.f, 0.f, 0.f, 0.f};
  float den = 0.f;
  if (cnt > 0 && g < cnt) {
    const int cm = cnt - 1;
    // register-sourced src ids (clamped; dummy loads never processed)
    int e1 = g + 4, e2 = g + 8;
    int s0 = __shfl(sv, g, 64);
    int s1 = __shfl(sv, e1 < cm ? e1 : cm, 64);
    int s2 = __shfl(sv, e2 < cm ? e2 : cm, 64);
    uint4 U0 = pb4[(size_t)s0 * 32 + m];
    uint4 U1 = pb4[(size_t)s1 * 32 + m];
    uint4 U2 = pb4[(size_t)s2 * 32 + m];
#pragma unroll 2
    for (int e = g; e < cnt; e += 4) {
      int e3 = e + 12;
      int s3 = __shfl(sv, e3 < cm ? e3 : cm, 64);
      uint4 U3 = pb4[(size_t)s3 * 32 + m];  // 3-ahead, address from registers
      uint uu[4] = {U0.x, U0.y, U0.z, U0.w};
      float slo[4], shi[4];
      float vp = 0.f;
#pragma unroll
      for (int j = 0; j < 4; ++j) {
        slo[j] = bf_lo(uu[j]);
        shi[j] = bf_hi(uu[j]);
        float v0 = slo[j] + dplo[j];
        float v1 = shi[j] + dphi[j];
        v0 = fmaxf(v0, 0.2f * v0);  // leakyrelu: max(v, 0.2v), 2 ops
        v1 = fmaxf(v1, 0.2f * v1);
        vp = fmaf(v0, avlo[j], vp);
        vp = fmaf(v1, avhi[j], vp);
      }
      vp += __shfl_xor(vp, 1, 64);  // head-local reduce (4-lane subgroup)
      vp += __shfl_xor(vp, 2, 64);
      float e_ = __expf(vp);
#pragma unroll
      for (int j = 0; j < 4; ++j) {
        acl[j] = fmaf(e_, slo[j], acl[j]);
        ach[j] = fmaf(e_, shi[j], ach[j]);
      }
      den += e_;
      U0 = U1;
      U1 = U2;
      U2 = U3;
    }
  }
  // combine the 4 edge-groups (heads preserved: lanes with same m align)
#pragma unroll
  for (int off = 16; off < 64; off <<= 1) {
    den += __shfl_xor(den, off, 64);
#pragma unroll
    for (int j = 0; j < 4; ++j) {
      acl[j] += __shfl_xor(acl[j], off, 64);
      ach[j] += __shfl_xor(ach[j], off, 64);
    }
  }
  if (g == 0) {
    float a = pa[0];
    float r = 1.f / (den + 1e-16f);
#pragma unroll
    for (int j = 0; j < 4; ++j) {
      float o0 = acl[j] * r + x[(size_t)d * FF + cl[j]] + bias[cl[j]];
      float o1 = ach[j] * r + x[(size_t)d * FF + cl[j] + 16] + bias[cl[j] + 16];
      out[(size_t)d * FF + cl[j]] = (o0 >= 0.f) ? o0 : a * o0;
      out[(size_t)d * FF + cl[j] + 16] = (o1 >= 0.f) ? o1 : a * o1;
    }
  }
}

extern "C" void kernel_launch(void* const* d_in, const int* in_sizes, int n_in,
                              void* d_out, int out_size, void* d_ws, size_t ws_size,
                              hipStream_t stream) {
  const float* x = (const float*)d_in[0];
  const int* ei = (const int*)d_in[1];
  const float* bws = (const float*)d_in[2];
  const float* sws = (const float*)d_in[3];
  const float* bwd = (const float*)d_in[4];
  const float* swd = (const float*)d_in[5];
  const float* av = (const float*)d_in[6];
  const float* bias = (const float*)d_in[7];
  const float* pa = (const float*)d_in[8];

  // ws layout: Wh | projB | cur | scsr(ushort, NN*CAP) | projF
  ushort* Wh = (ushort*)d_ws;
  uint* projB = (uint*)(Wh + (size_t)O2 * KT);
  int* cur = (int*)(projB + (size_t)NN * 128);
  ushort* scsr = (ushort*)(cur + NN);
  float2* projF = (float2*)(scsr + (size_t)NN * CAP);  // 7.3 MB

  repack_zero_kernel<<<(O2 * KT + 255) / 256, 256, 0, stream>>>(bws, sws, bwd, swd, Wh, cur);
  proj_fill_kernel<<<NPB + NTB2, 256, 0, stream>>>(x, Wh, projB, projF, ei, cur, scsr);
  pack_kernel<<<NPACK, 256, 0, stream>>>(projF, projB);
  aggr_kernel<<<(NN + 3) / 4, 256, 0, stream>>>(projB, scsr, cur, av, x, bias, pa,
                                                (float*)d_out);
}